// Round 1
// baseline (967.876 us; speedup 1.0000x reference)
//
#include <hip/hip_runtime.h>
#include <hip/hip_bf16.h>
#include <stdint.h>

#define FDIM 128

typedef short bf16x8 __attribute__((ext_vector_type(8)));
typedef float f32x4 __attribute__((ext_vector_type(4)));

__device__ __forceinline__ unsigned short f2bf(float f) {
    union { float f; unsigned int u; } v; v.f = f;
    unsigned int r = v.u + 0x7FFFu + ((v.u >> 16) & 1u);
    return (unsigned short)(r >> 16);
}
__device__ __forceinline__ unsigned int pack2bf(float a, float b) {
    return (unsigned int)f2bf(a) | ((unsigned int)f2bf(b) << 16);
}

// ---------------- prep: build pre-swizzled bf16 B-matrices + fused constants ----------------
// BT1[n][k], n in [0,128), k in [0,256): k<128 -> wNext[k][n] else wPrev[k-128][n]
// BT2[n][k], n in [0,512), k in [0,256):
//   n<256   : k<128 ? gk[k][n]     : gr[k-128][n]        (z-sum cols 0..127, r-sum cols 128..255)
//   n<384   : k<128 ? gk[k][n]     : 0                    (xh, col n)
//   else    : k<128 ? 0            : gr[k-128][n-128]     (rh, col n-128)
// swizzled store: byte = n*512 + ((2k) ^ ((n&15)<<4))
__global__ void prep_kernel(const float* __restrict__ wNext, const float* __restrict__ wPrev,
                            const float* __restrict__ gk, const float* __restrict__ gr,
                            const float* __restrict__ gb, const float* __restrict__ gamma,
                            const float* __restrict__ beta, const float* __restrict__ mean,
                            const float* __restrict__ var,
                            unsigned short* __restrict__ bt1, unsigned short* __restrict__ bt2,
                            float* __restrict__ bias2, float* __restrict__ bnscale,
                            float* __restrict__ bnshift)
{
    int t = blockIdx.x * blockDim.x + threadIdx.x;
    if (t < 32768) {
        int n = t >> 8, k = t & 255;
        float v = (k < 128) ? wNext[k * 128 + n] : wPrev[(k - 128) * 128 + n];
        unsigned int byte = (unsigned)n * 512u + (((unsigned)(k * 2)) ^ (((unsigned)(n & 15)) << 4));
        *(unsigned short*)((unsigned char*)bt1 + byte) = f2bf(v);
    } else if (t < 32768 + 131072) {
        int e = t - 32768;
        int n = e >> 8, k = e & 255;
        float v;
        if (n < 256)      v = (k < 128) ? gk[k * 384 + n] : gr[(k - 128) * 384 + n];
        else if (n < 384) v = (k < 128) ? gk[k * 384 + n] : 0.f;
        else              v = (k < 128) ? 0.f : gr[(k - 128) * 384 + (n - 128)];
        unsigned int byte = (unsigned)n * 512u + (((unsigned)(k * 2)) ^ (((unsigned)(n & 15)) << 4));
        *(unsigned short*)((unsigned char*)bt2 + byte) = f2bf(v);
    } else if (t < 32768 + 131072 + 512) {
        int n = t - (32768 + 131072);
        float v;
        if (n < 256)      v = gb[n] + gb[384 + n];          // z,r: bias0 + bias1
        else if (n < 384) v = gb[n];                         // xh: bias0[n]
        else              v = gb[384 + (n - 128)];           // rh: bias1[n-128]
        bias2[n] = v;
    } else if (t < 32768 + 131072 + 512 + 128) {
        int f = t - (32768 + 131072 + 512);
        float s = gamma[f] * rsqrtf(var[f] + 1e-3f);
        bnscale[f] = s;
        bnshift[f] = beta[f] - mean[f] * s;
    }
}

// ---------------- k1: gather + [sN|sP] @ [Wn;Wp] + b + x -> relu -> BN -> a (bf16, pre-swizzled)
__global__ __launch_bounds__(512, 1) void k1_gather_gemm(
    const float* __restrict__ x, const int* __restrict__ pprev, const int* __restrict__ pnext,
    const float* __restrict__ bvec, const unsigned short* __restrict__ bt1,
    const float* __restrict__ bnscale, const float* __restrict__ bnshift,
    unsigned short* __restrict__ a_ws, int Nn)
{
    __shared__ __align__(16) unsigned char ldsA[128 * 512];
    __shared__ __align__(16) unsigned char ldsB[128 * 512];
    const int tid = threadIdx.x, wid = tid >> 6, lane = tid & 63;
    const int base = blockIdx.x * 128;

    // stage BT1 (64KB), linear copy of pre-swizzled data
    {
        const uint4* src = (const uint4*)bt1;
        uint4* dst = (uint4*)ldsB;
#pragma unroll
        for (int i = 0; i < 8; i++) dst[i * 512 + tid] = src[i * 512 + tid];
    }
    // stage A tile: wave w owns rows 16w..16w+15; k<128 = sumNext, k>=128 = sumPrev
    {
        const float2* x2 = (const float2*)x;
        int rb = wid * 16;
        for (int j = 0; j < 16; j++) {
            int r = rb + j;
            int grow = base + r;
            unsigned int swz = ((unsigned)(r & 15)) << 4;
            unsigned int addrN = (unsigned)r * 512u + (((unsigned)(lane * 4)) ^ swz);
            unsigned int addrP = (unsigned)r * 512u + (((unsigned)(256 + lane * 4)) ^ swz);
            if (grow < Nn) {
                int4 pn = *(const int4*)(pnext + 4 * grow);
                int4 pp = *(const int4*)(pprev + 4 * grow);
                float2 a0 = x2[(size_t)pn.y * 64 + lane];
                float2 a1 = x2[(size_t)pn.w * 64 + lane];
                float2 b0 = x2[(size_t)pp.y * 64 + lane];
                float2 b1 = x2[(size_t)pp.w * 64 + lane];
                *(unsigned int*)(ldsA + addrN) = pack2bf(a0.x + a1.x, a0.y + a1.y);
                *(unsigned int*)(ldsA + addrP) = pack2bf(b0.x + b1.x, b0.y + b1.y);
            } else {
                *(unsigned int*)(ldsA + addrN) = 0u;
                *(unsigned int*)(ldsA + addrP) = 0u;
            }
        }
    }
    __syncthreads();

    const int col0 = lane & 15, kq = lane >> 4, rb = wid * 16;
    const unsigned int rs = ((unsigned)col0) << 4;
    bf16x8 af[8];
    {
        const unsigned char* Ap = ldsA + (rb + col0) * 512;
#pragma unroll
        for (int kk = 0; kk < 8; kk++)
            af[kk] = *(const bf16x8*)(Ap + (((unsigned)(kk * 64 + kq * 16)) ^ rs));
    }
    f32x4 acc[8];
#pragma unroll
    for (int nt = 0; nt < 8; nt++) acc[nt] = (f32x4){0.f, 0.f, 0.f, 0.f};
#pragma unroll
    for (int nt = 0; nt < 8; nt++) {
        const unsigned char* Bp = ldsB + (nt * 16 + col0) * 512;
#pragma unroll
        for (int kk = 0; kk < 8; kk++) {
            bf16x8 bf = *(const bf16x8*)(Bp + (((unsigned)(kk * 64 + kq * 16)) ^ rs));
            acc[nt] = __builtin_amdgcn_mfma_f32_16x16x32_bf16(af[kk], bf, acc[nt], 0, 0, 0);
        }
    }
    // epilogue: + b + x, relu, BN, store bf16 pre-swizzled for k2's linear LDS copy
#pragma unroll
    for (int nt = 0; nt < 8; nt++) {
        int col = nt * 16 + col0;
        float bb = bvec[col], sc = bnscale[col], sh = bnshift[col];
#pragma unroll
        for (int i = 0; i < 4; i++) {
            int r = rb + kq * 4 + i;
            int grow = base + r;
            if (grow < Nn) {
                float v = acc[nt][i] + bb + x[(size_t)grow * FDIM + col];
                v = fmaxf(v, 0.f) * sc + sh;
                unsigned int byte = (unsigned)grow * 256u +
                                    (((unsigned)(col * 2)) ^ (((unsigned)(r & 15)) << 4));
                *(unsigned short*)((unsigned char*)a_ws + byte) = f2bf(v);
            }
        }
    }
}

// ---------------- k2: [a|x] @ BT2 (512 cols) + GRU elementwise -> out ----------------
__global__ __launch_bounds__(512, 1) void k2_gemm_gru(
    const float* __restrict__ x, const unsigned short* __restrict__ a_ws,
    const unsigned short* __restrict__ bt2, const float* __restrict__ bias2,
    float* __restrict__ out, int Nn)
{
    __shared__ __align__(16) unsigned char ldsA[128 * 512];
    __shared__ __align__(16) unsigned char ldsB[64 * 512];
    const int tid = threadIdx.x, wid = tid >> 6, lane = tid & 63;
    const int base = blockIdx.x * 128;

    // stage A first half: a rows (already swizzled in ws), linear copy
    {
#pragma unroll
        for (int i = 0; i < 4; i++) {
            unsigned int s = (unsigned)i * 8192u + (unsigned)tid * 16u;
            int row = (int)(s >> 8);
            unsigned int within = s & 255u;
            uint4 v = {0u, 0u, 0u, 0u};
            int grow = base + row;
            if (grow < Nn)
                v = *(const uint4*)((const unsigned char*)a_ws + (unsigned)grow * 256u + within);
            *(uint4*)(ldsA + (unsigned)row * 512u + within) = v;
        }
    }
    // stage A second half: x converted to bf16, swizzled writes
    {
        int r = tid >> 2, q = tid & 3;
        int grow = base + r;
        unsigned int swz = ((unsigned)(r & 15)) << 4;
        const float4* x4 = (const float4*)x;
#pragma unroll
        for (int jj = 0; jj < 4; jj++) {
            uint4 pk = {0u, 0u, 0u, 0u};
            if (grow < Nn) {
                float4 v0 = x4[(size_t)grow * 32 + q * 8 + jj * 2];
                float4 v1 = x4[(size_t)grow * 32 + q * 8 + jj * 2 + 1];
                pk.x = pack2bf(v0.x, v0.y); pk.y = pack2bf(v0.z, v0.w);
                pk.z = pack2bf(v1.x, v1.y); pk.w = pack2bf(v1.z, v1.w);
            }
            unsigned int cb = (unsigned)(256 + q * 64 + jj * 16);
            *(uint4*)(ldsA + (unsigned)r * 512u + (cb ^ swz)) = pk;
        }
    }
    __syncthreads();

    const int col0 = lane & 15, kq = lane >> 4, rb = wid * 16;
    const unsigned int rs = ((unsigned)col0) << 4;
    bf16x8 af[8];
    {
        const unsigned char* Ap = ldsA + (rb + col0) * 512;
#pragma unroll
        for (int kk = 0; kk < 8; kk++)
            af[kk] = *(const bf16x8*)(Ap + (((unsigned)(kk * 64 + kq * 16)) ^ rs));
    }
    f32x4 acc[32];
#pragma unroll
    for (int nt = 0; nt < 32; nt++) acc[nt] = (f32x4){0.f, 0.f, 0.f, 0.f};

    const uint4* btg = (const uint4*)bt2;
    uint4 breg[4];
#pragma unroll
    for (int j = 0; j < 4; j++) breg[j] = btg[j * 512 + tid];

#pragma unroll
    for (int c = 0; c < 8; c++) {
        __syncthreads();   // previous chunk's compute done -> ldsB reusable
#pragma unroll
        for (int j = 0; j < 4; j++) *(uint4*)(ldsB + (j * 512 + tid) * 16) = breg[j];
        if (c < 7) {
#pragma unroll
            for (int j = 0; j < 4; j++) breg[j] = btg[(c + 1) * 2048 + j * 512 + tid];
        }
        __syncthreads();   // ldsB chunk ready
#pragma unroll
        for (int ntl = 0; ntl < 4; ntl++) {
            const int nt = c * 4 + ntl;
            const unsigned char* Bp = ldsB + (ntl * 16 + col0) * 512;
#pragma unroll
            for (int kk = 0; kk < 8; kk++) {
                bf16x8 bf = *(const bf16x8*)(Bp + (((unsigned)(kk * 64 + kq * 16)) ^ rs));
                acc[nt] = __builtin_amdgcn_mfma_f32_16x16x32_bf16(af[kk], bf, acc[nt], 0, 0, 0);
            }
        }
    }

    // GRU epilogue: cols [0,128)=z-sum, [128,256)=r-sum, [256,384)=xh, [384,512)=rh
#pragma unroll
    for (int nt = 0; nt < 8; nt++) {
        int f = nt * 16 + col0;
        float cz = bias2[f], cr = bias2[128 + f], cxh = bias2[256 + f], crh = bias2[384 + f];
#pragma unroll
        for (int i = 0; i < 4; i++) {
            int r = rb + kq * 4 + i;
            int grow = base + r;
            if (grow < Nn) {
                float zs = acc[nt][i] + cz;
                float rsum = acc[nt + 8][i] + cr;
                float xh = acc[nt + 16][i] + cxh;
                float rh = acc[nt + 24][i] + crh;
                float z = 1.f / (1.f + __expf(-zs));
                float rr = 1.f / (1.f + __expf(-rsum));
                float u = xh + rr * rh;
                float au = fabsf(u);
                float t = __expf(2.f * au);
                float th = 1.f - 2.f / (t + 1.f);
                float hh = (u >= 0.f) ? th : -th;
                float xv = x[(size_t)grow * FDIM + f];
                out[(size_t)grow * FDIM + f] = z * xv + (1.f - z) * hh;
            }
        }
    }
}

extern "C" void kernel_launch(void* const* d_in, const int* in_sizes, int n_in,
                              void* d_out, int out_size, void* d_ws, size_t ws_size,
                              hipStream_t stream)
{
    const float* x      = (const float*)d_in[0];
    const int*   pprev  = (const int*)d_in[1];
    const int*   pnext  = (const int*)d_in[2];
    const float* wNext  = (const float*)d_in[3];
    const float* wPrev  = (const float*)d_in[4];
    const float* b      = (const float*)d_in[5];
    const float* gk     = (const float*)d_in[6];
    const float* gr     = (const float*)d_in[7];
    const float* gb     = (const float*)d_in[8];
    const float* gamma  = (const float*)d_in[9];
    const float* beta   = (const float*)d_in[10];
    const float* mean   = (const float*)d_in[11];
    const float* var    = (const float*)d_in[12];
    float* out = (float*)d_out;
    const int Nn = in_sizes[0] / FDIM;

    unsigned char* ws = (unsigned char*)d_ws;
    unsigned short* bt1   = (unsigned short*)(ws + 0);
    unsigned short* bt2   = (unsigned short*)(ws + 65536);
    float* bias2          = (float*)(ws + 65536 + 262144);
    float* bnscale        = (float*)(ws + 65536 + 262144 + 2048);
    float* bnshift        = (float*)(ws + 65536 + 262144 + 2048 + 512);
    unsigned short* a_ws  = (unsigned short*)(ws + (1 << 20));   // N*256 bytes

    prep_kernel<<<643, 256, 0, stream>>>(wNext, wPrev, gk, gr, gb, gamma, beta, mean, var,
                                         bt1, bt2, bias2, bnscale, bnshift);
    const int nblocks = (Nn + 127) / 128;
    k1_gather_gemm<<<nblocks, 512, 0, stream>>>(x, pprev, pnext, b, bt1, bnscale, bnshift,
                                                a_ws, Nn);
    k2_gemm_gru<<<nblocks, 512, 0, stream>>>(x, a_ws, bt2, bias2, out, Nn);
}

// Round 2
// 712.018 us; speedup vs baseline: 1.3593x; 1.3593x over previous
//
#include <hip/hip_runtime.h>
#include <hip/hip_bf16.h>
#include <stdint.h>

#define FDIM 128

typedef short bf16x8 __attribute__((ext_vector_type(8)));
typedef float f32x4 __attribute__((ext_vector_type(4)));

__device__ __forceinline__ unsigned short f2bf(float f) {
    union { float f; unsigned int u; } v; v.f = f;
    unsigned int r = v.u + 0x7FFFu + ((v.u >> 16) & 1u);
    return (unsigned short)(r >> 16);
}
__device__ __forceinline__ unsigned int pack2bf(float a, float b) {
    return (unsigned int)f2bf(a) | ((unsigned int)f2bf(b) << 16);
}
__device__ __forceinline__ float bflo(unsigned int u) {
    union { unsigned int u; float f; } v; v.u = u << 16; return v.f;
}
__device__ __forceinline__ float bfhi(unsigned int u) {
    union { unsigned int u; float f; } v; v.u = u & 0xFFFF0000u; return v.f;
}
__device__ __forceinline__ float bf2f(unsigned short u) {
    union { unsigned int u; float f; } v; v.u = (unsigned int)u << 16; return v.f;
}

// ---------------- prep: pre-swizzled bf16 B-matrices (adjacent: bt1 64KB, bt2 256KB) ----------------
__global__ void prep_kernel(const float* __restrict__ wNext, const float* __restrict__ wPrev,
                            const float* __restrict__ gk, const float* __restrict__ gr,
                            const float* __restrict__ gb, const float* __restrict__ gamma,
                            const float* __restrict__ beta, const float* __restrict__ mean,
                            const float* __restrict__ var,
                            unsigned short* __restrict__ bt1, unsigned short* __restrict__ bt2,
                            float* __restrict__ bias2, float* __restrict__ bnscale,
                            float* __restrict__ bnshift)
{
    int t = blockIdx.x * blockDim.x + threadIdx.x;
    if (t < 32768) {
        int n = t >> 8, k = t & 255;
        float v = (k < 128) ? wNext[k * 128 + n] : wPrev[(k - 128) * 128 + n];
        unsigned int byte = (unsigned)n * 512u + (((unsigned)(k * 2)) ^ (((unsigned)(n & 15)) << 4));
        *(unsigned short*)((unsigned char*)bt1 + byte) = f2bf(v);
    } else if (t < 32768 + 131072) {
        int e = t - 32768;
        int n = e >> 8, k = e & 255;
        float v;
        if (n < 256)      v = (k < 128) ? gk[k * 384 + n] : gr[(k - 128) * 384 + n];
        else if (n < 384) v = (k < 128) ? gk[k * 384 + n] : 0.f;
        else              v = (k < 128) ? 0.f : gr[(k - 128) * 384 + (n - 128)];
        unsigned int byte = (unsigned)n * 512u + (((unsigned)(k * 2)) ^ (((unsigned)(n & 15)) << 4));
        *(unsigned short*)((unsigned char*)bt2 + byte) = f2bf(v);
    } else if (t < 32768 + 131072 + 512) {
        int n = t - (32768 + 131072);
        float v;
        if (n < 256)      v = gb[n] + gb[384 + n];
        else if (n < 384) v = gb[n];
        else              v = gb[384 + (n - 128)];
        bias2[n] = v;
    } else if (t < 32768 + 131072 + 512 + 128) {
        int f = t - (32768 + 131072 + 512);
        float s = gamma[f] * rsqrtf(var[f] + 1e-3f);
        bnscale[f] = s;
        bnshift[f] = beta[f] - mean[f] * s;
    }
}

// ---------------- x_convert: x f32 -> pre-swizzled bf16 rows (256B/row) ----------------
__global__ __launch_bounds__(256) void x_convert(const float* __restrict__ x,
                                                 unsigned short* __restrict__ xbf, int Nn)
{
    const int total = Nn * 32;   // one thread per 4 columns (16B read, 8B write)
    const float4* x4 = (const float4*)x;
    for (int t = blockIdx.x * 256 + threadIdx.x; t < total; t += gridDim.x * 256) {
        int m = t >> 5, l = t & 31;
        float4 v = x4[t];
        unsigned int lo = pack2bf(v.x, v.y), hi = pack2bf(v.z, v.w);
        unsigned int byte = (unsigned)m * 256u + (((unsigned)(l * 8)) ^ (((unsigned)(m & 15)) << 4));
        uint2 pk; pk.x = lo; pk.y = hi;
        *(uint2*)((unsigned char*)xbf + byte) = pk;
    }
}

// ---------------- g_gather: high-occupancy gather+sum, writes [sumNext|sumPrev] bf16 swizzled ----------------
__global__ __launch_bounds__(256) void g_gather(const unsigned short* __restrict__ xbf,
                                                const int* __restrict__ pprev,
                                                const int* __restrict__ pnext,
                                                unsigned short* __restrict__ s_ws, int Nn)
{
    const int lane = threadIdx.x & 63;
    const int wg = blockIdx.x * 4 + (threadIdx.x >> 6);
    const int nw = gridDim.x * 4;
    const unsigned int o = (unsigned)lane * 4u;
    const unsigned char* xb = (const unsigned char*)xbf;
    for (int nb = wg * 4; nb < Nn; nb += nw * 4) {
#pragma unroll
        for (int u = 0; u < 4; u++) {
            int n = nb + u;
            if (n < Nn) {
                int i0 = pnext[4 * n + 1], i1 = pnext[4 * n + 3];
                int j0 = pprev[4 * n + 1], j1 = pprev[4 * n + 3];
                unsigned int a0 = *(const unsigned int*)(xb + (size_t)i0 * 256u + (o ^ (((unsigned)(i0 & 15)) << 4)));
                unsigned int a1 = *(const unsigned int*)(xb + (size_t)i1 * 256u + (o ^ (((unsigned)(i1 & 15)) << 4)));
                unsigned int b0 = *(const unsigned int*)(xb + (size_t)j0 * 256u + (o ^ (((unsigned)(j0 & 15)) << 4)));
                unsigned int b1 = *(const unsigned int*)(xb + (size_t)j1 * 256u + (o ^ (((unsigned)(j1 & 15)) << 4)));
                float nx0 = bflo(a0) + bflo(a1), nx1 = bfhi(a0) + bfhi(a1);
                float px0 = bflo(b0) + bflo(b1), px1 = bfhi(b0) + bfhi(b1);
                unsigned int swz = ((unsigned)(n & 15)) << 4;
                unsigned char* row = (unsigned char*)s_ws + (size_t)n * 512u;
                *(unsigned int*)(row + (o ^ swz)) = pack2bf(nx0, nx1);
                *(unsigned int*)(row + 256u + (o ^ swz)) = pack2bf(px0, px1);
            }
        }
    }
}

// ---------------- m_fused: GEMM1 (+b+x, relu, BN) -> GEMM2 -> GRU, all in one block pass ----------------
__global__ __launch_bounds__(512, 2) void m_fused(
    const unsigned short* __restrict__ s_ws, const unsigned short* __restrict__ xbf,
    const unsigned short* __restrict__ btAll, const float* __restrict__ bvec,
    const float* __restrict__ bnscale, const float* __restrict__ bnshift,
    const float* __restrict__ bias2, float* __restrict__ out, int Nn)
{
    __shared__ __align__(16) unsigned char lds[131072];
    unsigned char* bufS = lds;              // 64KB [sN|sP] tile; front 32KB later = a-tile
    unsigned char* bufB = lds + 65536;      // 32KB B chunk
    unsigned char* bufX = lds + 98304;      // 32KB x bf16 tile
    const int tid = threadIdx.x, wid = tid >> 6, lane = tid & 63;
    const int base = blockIdx.x * 128;

    // prefetch B chunk 0 into registers
    const uint4* bt16 = (const uint4*)btAll;
    uint4 breg[4];
#pragma unroll
    for (int j = 0; j < 4; j++) breg[j] = bt16[j * 512 + tid];

    // stage bufS <- s_ws tile (64KB, linear, pre-swizzled source)
#pragma unroll
    for (int j = 0; j < 8; j++) {
        int blk = wid * 8 + j;
        if (base + blk * 2 < Nn)
            __builtin_amdgcn_global_load_lds(
                (const __attribute__((address_space(1))) unsigned int*)
                    ((const unsigned char*)s_ws + (size_t)base * 512u + (unsigned)blk * 1024u + (unsigned)lane * 16u),
                (__attribute__((address_space(3))) unsigned int*)(bufS + (unsigned)blk * 1024u),
                16, 0, 0);
    }
    // stage bufX <- xbf tile (32KB, linear, pre-swizzled source)
#pragma unroll
    for (int j = 0; j < 4; j++) {
        int blk = wid * 4 + j;
        if (base + blk * 4 < Nn)
            __builtin_amdgcn_global_load_lds(
                (const __attribute__((address_space(1))) unsigned int*)
                    ((const unsigned char*)xbf + (size_t)base * 256u + (unsigned)blk * 1024u + (unsigned)lane * 16u),
                (__attribute__((address_space(3))) unsigned int*)(bufX + (unsigned)blk * 1024u),
                16, 0, 0);
    }
    __syncthreads();

    const int col0 = lane & 15, kq = lane >> 4, rb = wid * 16;
    const unsigned int rs = ((unsigned)col0) << 4;

    // A1 fragments: wave's own 16 rows of [sN|sP] (K=256)
    bf16x8 af[8];
#pragma unroll
    for (int kk = 0; kk < 8; kk++)
        af[kk] = *(const bf16x8*)(bufS + (rb + col0) * 512 + (((unsigned)(kk * 64 + kq * 16)) ^ rs));

    // ---- GEMM1: 2 chunks of 64 cols ----
    f32x4 acc1[8];
#pragma unroll
    for (int nt = 0; nt < 8; nt++) acc1[nt] = (f32x4){0.f, 0.f, 0.f, 0.f};
#pragma unroll
    for (int c = 0; c < 2; c++) {
        __syncthreads();
#pragma unroll
        for (int j = 0; j < 4; j++) *(uint4*)(bufB + (j * 512 + tid) * 16) = breg[j];
#pragma unroll
        for (int j = 0; j < 4; j++) breg[j] = bt16[(c + 1) * 2048 + j * 512 + tid];
        __syncthreads();
#pragma unroll
        for (int ntl = 0; ntl < 4; ntl++) {
            const unsigned char* Bp = bufB + (ntl * 16 + col0) * 512;
#pragma unroll
            for (int kk = 0; kk < 8; kk++) {
                bf16x8 bf = *(const bf16x8*)(Bp + (((unsigned)(kk * 64 + kq * 16)) ^ rs));
                acc1[c * 4 + ntl] = __builtin_amdgcn_mfma_f32_16x16x32_bf16(af[kk], bf, acc1[c * 4 + ntl], 0, 0, 0);
            }
        }
    }

    // ---- epilogue1: + b + x, relu, BN -> a-tile (bf16, swizzled) in bufS front ----
#pragma unroll
    for (int nt = 0; nt < 8; nt++) {
        int col = nt * 16 + col0;
        float bb = bvec[col], sc = bnscale[col], sh = bnshift[col];
#pragma unroll
        for (int i = 0; i < 4; i++) {
            int r = rb + kq * 4 + i;
            if (base + r < Nn) {
                unsigned int sw = ((unsigned)(r & 15)) << 4;
                float xv = bf2f(*(const unsigned short*)(bufX + r * 256 + (((unsigned)(col * 2)) ^ sw)));
                float v = acc1[nt][i] + bb + xv;
                v = fmaxf(v, 0.f) * sc + sh;
                *(unsigned short*)(bufS + r * 256 + (((unsigned)(col * 2)) ^ sw)) = f2bf(v);
            }
        }
    }
    __syncthreads();

    // A2 fragments: [a | x] (K=256): kk 0-3 from a-tile, kk 4-7 from bufX
#pragma unroll
    for (int kk = 0; kk < 4; kk++)
        af[kk] = *(const bf16x8*)(bufS + (rb + col0) * 256 + (((unsigned)(kk * 64 + kq * 16)) ^ rs));
#pragma unroll
    for (int kk = 0; kk < 4; kk++)
        af[kk + 4] = *(const bf16x8*)(bufX + (rb + col0) * 256 + (((unsigned)(kk * 64 + kq * 16)) ^ rs));

    // ---- GEMM2: 8 chunks of 64 cols (512 total) ----
    f32x4 acc2[32];
#pragma unroll
    for (int nt = 0; nt < 32; nt++) acc2[nt] = (f32x4){0.f, 0.f, 0.f, 0.f};
#pragma unroll
    for (int c = 0; c < 8; c++) {
        __syncthreads();
#pragma unroll
        for (int j = 0; j < 4; j++) *(uint4*)(bufB + (j * 512 + tid) * 16) = breg[j];
        if (c < 7) {
#pragma unroll
            for (int j = 0; j < 4; j++) breg[j] = bt16[(c + 3) * 2048 + j * 512 + tid];
        }
        __syncthreads();
#pragma unroll
        for (int ntl = 0; ntl < 4; ntl++) {
            const unsigned char* Bp = bufB + (ntl * 16 + col0) * 512;
#pragma unroll
            for (int kk = 0; kk < 8; kk++) {
                bf16x8 bf = *(const bf16x8*)(Bp + (((unsigned)(kk * 64 + kq * 16)) ^ rs));
                acc2[c * 4 + ntl] = __builtin_amdgcn_mfma_f32_16x16x32_bf16(af[kk], bf, acc2[c * 4 + ntl], 0, 0, 0);
            }
        }
    }

    // ---- GRU epilogue: cols [0,128)=z, [128,256)=r, [256,384)=xh, [384,512)=rh ----
#pragma unroll
    for (int nt = 0; nt < 8; nt++) {
        int f = nt * 16 + col0;
        float cz = bias2[f], cr = bias2[128 + f], cxh = bias2[256 + f], crh = bias2[384 + f];
#pragma unroll
        for (int i = 0; i < 4; i++) {
            int r = rb + kq * 4 + i;
            int grow = base + r;
            if (grow < Nn) {
                float zs = acc2[nt][i] + cz;
                float rsum = acc2[nt + 8][i] + cr;
                float xh = acc2[nt + 16][i] + cxh;
                float rh = acc2[nt + 24][i] + crh;
                float z = 1.f / (1.f + __expf(-zs));
                float rr = 1.f / (1.f + __expf(-rsum));
                float u = xh + rr * rh;
                float au = fabsf(u);
                float t = __expf(2.f * au);
                float th = 1.f - 2.f / (t + 1.f);
                float hh = (u >= 0.f) ? th : -th;
                unsigned int sw = ((unsigned)(r & 15)) << 4;
                float xv = bf2f(*(const unsigned short*)(bufX + r * 256 + (((unsigned)(f * 2)) ^ sw)));
                out[(size_t)grow * FDIM + f] = z * xv + (1.f - z) * hh;
            }
        }
    }
}

extern "C" void kernel_launch(void* const* d_in, const int* in_sizes, int n_in,
                              void* d_out, int out_size, void* d_ws, size_t ws_size,
                              hipStream_t stream)
{
    const float* x      = (const float*)d_in[0];
    const int*   pprev  = (const int*)d_in[1];
    const int*   pnext  = (const int*)d_in[2];
    const float* wNext  = (const float*)d_in[3];
    const float* wPrev  = (const float*)d_in[4];
    const float* b      = (const float*)d_in[5];
    const float* gk     = (const float*)d_in[6];
    const float* gr     = (const float*)d_in[7];
    const float* gb     = (const float*)d_in[8];
    const float* gamma  = (const float*)d_in[9];
    const float* beta   = (const float*)d_in[10];
    const float* mean   = (const float*)d_in[11];
    const float* var    = (const float*)d_in[12];
    float* out = (float*)d_out;
    const int Nn = in_sizes[0] / FDIM;

    // ws layout: s_ws (N*512B) | xbf (N*256B) | btAll (320KB) | bias2 (2KB) | bnscale | bnshift
    unsigned char* ws = (unsigned char*)d_ws;
    unsigned short* s_ws = (unsigned short*)(ws + 0);
    size_t off_x  = (size_t)Nn * 512u;
    size_t off_bt = off_x + (size_t)Nn * 256u;
    unsigned short* xbf   = (unsigned short*)(ws + off_x);
    unsigned short* bt1   = (unsigned short*)(ws + off_bt);
    unsigned short* bt2   = (unsigned short*)(ws + off_bt + 65536);
    float* bias2          = (float*)(ws + off_bt + 327680);
    float* bnscale        = (float*)(ws + off_bt + 327680 + 2048);
    float* bnshift        = (float*)(ws + off_bt + 327680 + 2048 + 512);

    prep_kernel<<<643, 256, 0, stream>>>(wNext, wPrev, gk, gr, gb, gamma, beta, mean, var,
                                         bt1, bt2, bias2, bnscale, bnshift);
    x_convert<<<2048, 256, 0, stream>>>(x, xbf, Nn);
    g_gather<<<2048, 256, 0, stream>>>(xbf, pprev, pnext, s_ws, Nn);
    const int nblocks = (Nn + 127) / 128;
    m_fused<<<nblocks, 512, 0, stream>>>(s_ws, xbf, bt1, b, bnscale, bnshift, bias2, out, Nn);
}